// Round 1
// baseline (562.792 us; speedup 1.0000x reference)
//
#include <hip/hip_runtime.h>

typedef unsigned long long u64;
typedef unsigned int u32;

#define KC 1024
#define TOPK 750
#define CONF 0.3f
#define IOU_T 0.01f

// ---------------- K1: scores -> sortable keys ----------------
__global__ void k_scores(const float* __restrict__ cls, u64* __restrict__ keys, int P) {
    int p = blockIdx.x * 256 + threadIdx.x;
    int b = blockIdx.y;
    if (p >= P) return;
    const float* c2 = cls + ((size_t)b * P + p) * 2;
    float a0 = c2[0], a1 = c2[1];
    float m  = fmaxf(a0, a1);
    float e0 = expf(a0 - m), e1 = expf(a1 - m);
    float s  = e1 / (e0 + e1);
    float ms = s > CONF ? s : -1.0f;
    u32 u = __float_as_uint(ms);
    u32 mapped = (u & 0x80000000u) ? ~u : (u | 0x80000000u);  // monotone f32->u32
    // tie-break: smaller prior index first => ~p in low bits
    keys[(size_t)b * P + p] = ((u64)mapped << 32) | (u32)(~(u32)p);
}

// ---------------- K2: exact top-1024 (radix select + bitonic sort) ----------------
__global__ __launch_bounds__(1024) void k_select(const u64* __restrict__ keys,
                                                 u64* __restrict__ cand, int P) {
    int b = blockIdx.x, tid = threadIdx.x;
    const u64* kb = keys + (size_t)b * P;
    __shared__ u32 hist[16][256];
    __shared__ u64 sh_prefix;
    __shared__ u32 sh_r;
    __shared__ u64 keys2[KC];
    __shared__ u32 cnt;
    int wv = tid >> 6;

    if (tid == 0) { sh_prefix = 0ull; sh_r = KC; }

    for (int pass = 0; pass < 8; ++pass) {
        for (int i = tid; i < 16 * 256; i += 1024) ((u32*)hist)[i] = 0;
        __syncthreads();
        u64 prefix = sh_prefix;
        u32 r = sh_r;
        int shiftd = 56 - 8 * pass;
        for (int i = tid; i < P; i += 1024) {
            u64 k = kb[i];
            bool match;
            if (pass == 0) match = true;
            else           match = (k >> (shiftd + 8)) == prefix;
            if (match) atomicAdd(&hist[wv][(u32)((k >> shiftd) & 255ull)], 1u);
        }
        __syncthreads();
        if (tid < 256) {
            u32 s = 0;
            for (int w = 0; w < 16; ++w) s += hist[w][tid];
            hist[0][tid] = s;
        }
        __syncthreads();
        if (tid == 0) {
            u32 cum = 0; int v = 255;
            for (; v >= 0; --v) {
                u32 c = hist[0][v];
                if (cum + c >= r) { sh_r = r - cum; break; }
                cum += c;
            }
            sh_prefix = (prefix << 8) | (u64)(u32)v;
        }
        __syncthreads();
    }
    u64 cutoff = sh_prefix;   // exact 1024th-largest key (keys are unique)
    if (tid == 0) cnt = 0;
    __syncthreads();
    for (int i = tid; i < P; i += 1024) {
        u64 k = kb[i];
        if (k >= cutoff) {
            u32 pos = atomicAdd(&cnt, 1u);
            if (pos < KC) keys2[pos] = k;
        }
    }
    __syncthreads();
    // bitonic sort descending, 1024 elems / 1024 threads
    for (int kk = 2; kk <= KC; kk <<= 1) {
        for (int j = kk >> 1; j > 0; j >>= 1) {
            int pr = tid ^ j;
            u64 a = keys2[tid], bb = keys2[pr];
            bool lower = tid < pr;
            bool descR = (tid & kk) == 0;
            u64 mn = a < bb ? a : bb;
            u64 mx = a < bb ? bb : a;
            u64 nv = (descR == lower) ? mx : mn;
            __syncthreads();
            keys2[tid] = nv;
            __syncthreads();
        }
    }
    cand[(size_t)b * KC + tid] = keys2[tid];
}

// ---------------- K3: decode + NMS + output ----------------
__global__ __launch_bounds__(1024) void k_nms(const u64* __restrict__ cand,
                                              const float* __restrict__ boxes_logits,
                                              const float* __restrict__ priors,
                                              u64* __restrict__ rows,
                                              float* __restrict__ out, int P, int B) {
    int b = blockIdx.x, tid = threadIdx.x;
    __shared__ float sbox[KC][4];
    __shared__ float sscore[KC];
    __shared__ int   svalid[KC];
    __shared__ float smax[KC];
    __shared__ u64   keepw[16];

    u64 key = cand[(size_t)b * KC + tid];
    u32 mapped = (u32)(key >> 32);
    u32 fb = (mapped & 0x80000000u) ? (mapped & 0x7fffffffu) : ~mapped;
    float score = __uint_as_float(fb);
    u32 p = ~(u32)(key & 0xffffffffull);
    bool valid = score > CONF;

    // decode (exact f32 op order of the reference)
    const float* pr = priors + (size_t)p * 4;
    const float* lc = boxes_logits + ((size_t)b * P + p) * 4;
    float pcx = pr[0], pcy = pr[1], pw = pr[2], ph = pr[3];
    float lx = lc[0], ly = lc[1], lw = lc[2], lh = lc[3];
    float cx = pcx + lx * 0.1f * pw;
    float cy = pcy + ly * 0.1f * ph;
    float w  = pw * expf(lw * 0.2f);
    float h  = ph * expf(lh * 0.2f);
    float t1x = cx - w * 0.5f;
    float t1y = cy - h * 0.5f;
    float x1 = t1x * 1024.0f;
    float y1 = t1y * 1024.0f;
    float x2 = (t1x + w) * 1024.0f;
    float y2 = (t1y + h) * 1024.0f;

    sbox[tid][0] = x1; sbox[tid][1] = y1; sbox[tid][2] = x2; sbox[tid][3] = y2;
    sscore[tid] = score;
    svalid[tid] = valid ? 1 : 0;
    // max_c over where(valid, cb, 0)
    float mc = valid ? fmaxf(fmaxf(x1, y1), fmaxf(x2, y2)) : 0.0f;
    smax[tid] = mc;
    __syncthreads();
    for (int s = 512; s > 0; s >>= 1) {
        if (tid < s) smax[tid] = fmaxf(smax[tid], smax[tid + s]);
        __syncthreads();
    }
    float off = smax[0] + 1.0f;   // class offset (label==1 for all)

    // my shifted box
    float bx1 = x1 + off, by1 = y1 + off, bx2 = x2 + off, by2 = y2 + off;
    float area_j = (bx2 - bx1) * (by2 - by1);

    u64* rb = rows + (size_t)b * KC * 16;
    for (int i = 0; i < KC; ++i) {
        float ix1 = sbox[i][0] + off, iy1 = sbox[i][1] + off;
        float ix2 = sbox[i][2] + off, iy2 = sbox[i][3] + off;
        float iarea = (ix2 - ix1) * (iy2 - iy1);
        float ltx = fmaxf(ix1, bx1), lty = fmaxf(iy1, by1);
        float rbx = fminf(ix2, bx2), rby = fminf(iy2, by2);
        float ww = fmaxf(rbx - ltx, 0.0f), hh = fmaxf(rby - lty, 0.0f);
        float inter = ww * hh;
        float uni = iarea + area_j - inter;
        float iou = inter / fmaxf(uni, 1e-9f);
        bool pred = (iou > IOU_T) && (i != tid);
        u64 m = __ballot(pred);
        if ((tid & 63) == 0) rb[(size_t)i * 16 + (tid >> 6)] = m;
    }
    __syncthreads();

    // sequential greedy scan: 16 lanes of wave 0 hold the 1024-bit suppressed mask
    if (tid < 16) {
        u64 supp = 0, kw = 0;
        for (int i = 0; i < KC; ++i) {
            int w2 = i >> 6, bit = i & 63;
            u64 sw = __shfl(supp, w2);
            bool ok = svalid[i] && !((sw >> bit) & 1ull);
            u64 row = rb[(size_t)i * 16 + tid];
            if (ok) {
                supp |= row;
                if (tid == w2) kw |= 1ull << bit;
            }
        }
        keepw[tid] = kw;
    }
    __syncthreads();

    int wq = tid >> 6, bq = tid & 63;
    u64 myw = keepw[wq];
    bool kept = (myw >> bq) & 1ull;
    int rank = 0, nk = 0;
    for (int w2 = 0; w2 < 16; ++w2) {
        int pc = __popcll(keepw[w2]);
        nk += pc;
        if (w2 < wq) rank += pc;
    }
    rank += __popcll(myw & ((1ull << bq) - 1ull));

    float* ob  = out;
    float* osc = out + (size_t)B * TOPK * 4;
    float* olb = osc + (size_t)B * TOPK;
    float* omk = olb + (size_t)B * TOPK;

    if (kept && rank < TOPK) {
        size_t o = (size_t)b * TOPK + rank;
        ob[o * 4 + 0] = sbox[tid][0];
        ob[o * 4 + 1] = sbox[tid][1];
        ob[o * 4 + 2] = sbox[tid][2];
        ob[o * 4 + 3] = sbox[tid][3];
        osc[o] = sscore[tid];
        olb[o] = 1.0f;
        omk[o] = 1.0f;
    }
    int zstart = nk < TOPK ? nk : TOPK;
    if (tid >= zstart && tid < TOPK) {
        size_t o = (size_t)b * TOPK + tid;
        ob[o * 4 + 0] = 0.0f; ob[o * 4 + 1] = 0.0f;
        ob[o * 4 + 2] = 0.0f; ob[o * 4 + 3] = 0.0f;
        osc[o] = 0.0f;
        olb[o] = 0.0f;
        omk[o] = 0.0f;
    }
}

extern "C" void kernel_launch(void* const* d_in, const int* in_sizes, int n_in,
                              void* d_out, int out_size, void* d_ws, size_t ws_size,
                              hipStream_t stream) {
    const float* boxes_logits = (const float*)d_in[0];
    const float* cls_logits   = (const float*)d_in[1];
    const float* priors       = (const float*)d_in[2];
    int P = in_sizes[2] / 4;
    int B = in_sizes[0] / (P * 4);
    float* out = (float*)d_out;

    u64* keys = (u64*)d_ws;
    u64* cand = (u64*)((char*)d_ws + (size_t)B * P * sizeof(u64));
    u64* rows = (u64*)d_ws;   // reuse keys region (dead after k_select)

    dim3 g1((P + 255) / 256, B);
    hipLaunchKernelGGL(k_scores, g1, dim3(256), 0, stream, cls_logits, keys, P);
    hipLaunchKernelGGL(k_select, dim3(B), dim3(1024), 0, stream, keys, cand, P);
    hipLaunchKernelGGL(k_nms, dim3(B), dim3(1024), 0, stream, cand, boxes_logits, priors,
                       rows, out, P, B);
}

// Round 2
// 265.238 us; speedup vs baseline: 2.1218x; 2.1218x over previous
//
#include <hip/hip_runtime.h>

typedef unsigned long long u64;
typedef unsigned int u32;

#define KC 1024
#define TOPK 750
#define CONF 0.3f
#define IOU_T 0.01f

// ---------------- K1: scores -> sortable keys ----------------
__global__ void k_scores(const float* __restrict__ cls, u64* __restrict__ keys, int P) {
    int p = blockIdx.x * 256 + threadIdx.x;
    int b = blockIdx.y;
    if (p >= P) return;
    const float* c2 = cls + ((size_t)b * P + p) * 2;
    float a0 = c2[0], a1 = c2[1];
    float m  = fmaxf(a0, a1);
    float e0 = expf(a0 - m), e1 = expf(a1 - m);
    float s  = e1 / (e0 + e1);
    float ms = s > CONF ? s : -1.0f;
    u32 u = __float_as_uint(ms);
    u32 mapped = (u & 0x80000000u) ? ~u : (u | 0x80000000u);  // monotone f32->u32
    keys[(size_t)b * P + p] = ((u64)mapped << 32) | (u32)(~(u32)p);
}

// ---------------- K2: top-1024 radix select + bitonic sort + decode ----------------
__global__ __launch_bounds__(1024) void k_select(const u64* __restrict__ keys,
                                                 const float* __restrict__ boxes_logits,
                                                 const float* __restrict__ priors,
                                                 float* __restrict__ cboxes,
                                                 float* __restrict__ cscores,
                                                 int*   __restrict__ cvalid,
                                                 float* __restrict__ coffs, int P) {
    int b = blockIdx.x, tid = threadIdx.x;
    const u64* kb = keys + (size_t)b * P;
    __shared__ u32 hist[16][256];
    __shared__ u32 suf[2][256];
    __shared__ u64 sh_prefix;
    __shared__ u32 sh_r;
    __shared__ int sh_v;
    __shared__ u64 keys2[KC];
    __shared__ u32 cnt;
    __shared__ float smax[KC];
    int wv = tid >> 6;

    if (tid == 0) { sh_prefix = 0ull; sh_r = KC; }

    for (int pass = 0; pass < 8; ++pass) {
        for (int i = tid; i < 16 * 256; i += 1024) ((u32*)hist)[i] = 0;
        if (tid == 0) sh_v = 0;
        __syncthreads();
        u64 prefix = sh_prefix;
        u32 r = sh_r;
        int shiftd = 56 - 8 * pass;
        for (int i = tid; i < P; i += 1024) {
            u64 k = kb[i];
            bool match = (pass == 0) || ((k >> (shiftd + 8)) == prefix);
            if (match) atomicAdd(&hist[wv][(u32)((k >> shiftd) & 255ull)], 1u);
        }
        __syncthreads();
        if (tid < 256) {
            u32 s = 0;
            #pragma unroll
            for (int w = 0; w < 16; ++w) s += hist[w][tid];
            hist[0][tid] = s;   // per-bin count
            suf[0][tid]  = s;
        }
        __syncthreads();
        int src = 0;
        for (int d = 1; d < 256; d <<= 1) {      // inclusive suffix sums, 8 steps
            if (tid < 256) suf[src ^ 1][tid] = suf[src][tid] + ((tid + d < 256) ? suf[src][tid + d] : 0u);
            src ^= 1;
            __syncthreads();
        }
        // src back to 0 after 8 toggles; suf[0][v] = sum_{u>=v} count(u)
        if (tid < 256 && suf[0][tid] >= r) atomicMax(&sh_v, tid);
        __syncthreads();
        if (tid == 0) {
            int v = sh_v;
            sh_r = r - (suf[0][v] - hist[0][v]);  // r - suffix_exclusive(v)
            sh_prefix = (prefix << 8) | (u64)(u32)v;
        }
        __syncthreads();
    }
    u64 cutoff = sh_prefix;   // exact 1024th-largest key (keys unique)
    if (tid == 0) cnt = 0;
    __syncthreads();
    for (int i = tid; i < P; i += 1024) {
        u64 k = kb[i];
        if (k >= cutoff) {
            u32 pos = atomicAdd(&cnt, 1u);
            if (pos < KC) keys2[pos] = k;
        }
    }
    __syncthreads();
    // bitonic sort descending
    for (int kk = 2; kk <= KC; kk <<= 1) {
        for (int j = kk >> 1; j > 0; j >>= 1) {
            int pr = tid ^ j;
            u64 a = keys2[tid], bb = keys2[pr];
            bool lower = tid < pr;
            bool descR = (tid & kk) == 0;
            u64 mn = a < bb ? a : bb;
            u64 mx = a < bb ? bb : a;
            u64 nv = (descR == lower) ? mx : mn;
            __syncthreads();
            keys2[tid] = nv;
            __syncthreads();
        }
    }

    // decode candidate tid (exact f32 op order of the reference)
    u64 key = keys2[tid];
    u32 mapped = (u32)(key >> 32);
    u32 fb = (mapped & 0x80000000u) ? (mapped & 0x7fffffffu) : ~mapped;
    float score = __uint_as_float(fb);
    u32 p = ~(u32)(key & 0xffffffffull);
    bool valid = score > CONF;

    const float* pr4 = priors + (size_t)p * 4;
    const float* lc  = boxes_logits + ((size_t)b * P + p) * 4;
    float pcx = pr4[0], pcy = pr4[1], pw = pr4[2], ph = pr4[3];
    float lx = lc[0], ly = lc[1], lw = lc[2], lh = lc[3];
    float cx = pcx + lx * 0.1f * pw;
    float cy = pcy + ly * 0.1f * ph;
    float w  = pw * expf(lw * 0.2f);
    float h  = ph * expf(lh * 0.2f);
    float t1x = cx - w * 0.5f;
    float t1y = cy - h * 0.5f;
    float x1 = t1x * 1024.0f;
    float y1 = t1y * 1024.0f;
    float x2 = (t1x + w) * 1024.0f;
    float y2 = (t1y + h) * 1024.0f;

    size_t ci = (size_t)b * KC + tid;
    cboxes[ci * 4 + 0] = x1; cboxes[ci * 4 + 1] = y1;
    cboxes[ci * 4 + 2] = x2; cboxes[ci * 4 + 3] = y2;
    cscores[ci] = score;
    cvalid[ci]  = valid ? 1 : 0;

    smax[tid] = valid ? fmaxf(fmaxf(x1, y1), fmaxf(x2, y2)) : 0.0f;
    __syncthreads();
    for (int s = 512; s > 0; s >>= 1) {
        if (tid < s) smax[tid] = fmaxf(smax[tid], smax[tid + s]);
        __syncthreads();
    }
    if (tid == 0) coffs[b] = smax[0] + 1.0f;
}

// ---------------- K3: IoU suppression bitmatrix (full-chip parallel) ----------------
__global__ __launch_bounds__(1024) void k_iou(const float* __restrict__ cboxes,
                                              const float* __restrict__ coffs,
                                              u64* __restrict__ rows) {
    int b = blockIdx.y, tid = threadIdx.x;
    int rowbase = blockIdx.x * 16;
    __shared__ float sx1[KC], sy1[KC], sx2[KC], sy2[KC], sar[KC];
    float off = coffs[b];
    const float* cb = cboxes + (size_t)b * KC * 4;
    float x1 = cb[(size_t)tid * 4 + 0] + off;
    float y1 = cb[(size_t)tid * 4 + 1] + off;
    float x2 = cb[(size_t)tid * 4 + 2] + off;
    float y2 = cb[(size_t)tid * 4 + 3] + off;
    sx1[tid] = x1; sy1[tid] = y1; sx2[tid] = x2; sy2[tid] = y2;
    sar[tid] = (x2 - x1) * (y2 - y1);
    __syncthreads();

    int w = tid >> 6, lane = tid & 63;
    int r = rowbase + w;
    float rx1 = sx1[r], ry1 = sy1[r], rx2 = sx2[r], ry2 = sy2[r], rar = sar[r];
    u64* rb = rows + ((size_t)b * KC + r) * 16;
    #pragma unroll 4
    for (int c = 0; c < 16; ++c) {
        int col = c * 64 + lane;
        float ltx = fmaxf(rx1, sx1[col]), lty = fmaxf(ry1, sy1[col]);
        float rbx = fminf(rx2, sx2[col]), rby = fminf(ry2, sy2[col]);
        float ww = fmaxf(rbx - ltx, 0.0f), hh = fmaxf(rby - lty, 0.0f);
        float inter = ww * hh;
        float uni = rar + sar[col] - inter;
        float iou = inter / fmaxf(uni, 1e-9f);
        bool pred = (iou > IOU_T) && (col != r);
        u64 m = __ballot(pred);
        if (lane == 0) rb[c] = m;
    }
}

// ---------------- K4: serial greedy scan + output ----------------
__global__ __launch_bounds__(1024) void k_scan(const u64* __restrict__ rows,
                                               const float* __restrict__ cboxes,
                                               const float* __restrict__ cscores,
                                               const int*   __restrict__ cvalid,
                                               float* __restrict__ out, int B) {
    int b = blockIdx.x, tid = threadIdx.x;
    __shared__ int svalid_s[KC];
    __shared__ u64 keepw[16];
    svalid_s[tid] = cvalid[(size_t)b * KC + tid];
    __syncthreads();

    const u64* rb = rows + (size_t)b * KC * 16;
    if (tid < 16) {
        u64 supp = 0, kw = 0;
        u64 nextrow = rb[tid];
        for (int i = 0; i < KC; ++i) {
            u64 row = nextrow;
            if (i + 1 < KC) nextrow = rb[(size_t)(i + 1) * 16 + tid];  // prefetch off critical path
            int w2 = i >> 6, bit = i & 63;
            u64 sw = __shfl(supp, w2);
            bool ok = svalid_s[i] && !((sw >> bit) & 1ull);
            if (ok) {
                supp |= row;
                if (tid == w2) kw |= 1ull << bit;
            }
        }
        keepw[tid] = kw;
    }
    __syncthreads();

    int wq = tid >> 6, bq = tid & 63;
    u64 myw = keepw[wq];
    bool kept = (myw >> bq) & 1ull;
    int rank = 0, nk = 0;
    for (int w2 = 0; w2 < 16; ++w2) {
        int pc = __popcll(keepw[w2]);
        nk += pc;
        if (w2 < wq) rank += pc;
    }
    rank += __popcll(myw & ((1ull << bq) - 1ull));

    float* ob  = out;
    float* osc = out + (size_t)B * TOPK * 4;
    float* olb = osc + (size_t)B * TOPK;
    float* omk = olb + (size_t)B * TOPK;

    size_t ci = (size_t)b * KC + tid;
    if (kept && rank < TOPK) {
        size_t o = (size_t)b * TOPK + rank;
        ob[o * 4 + 0] = cboxes[ci * 4 + 0];
        ob[o * 4 + 1] = cboxes[ci * 4 + 1];
        ob[o * 4 + 2] = cboxes[ci * 4 + 2];
        ob[o * 4 + 3] = cboxes[ci * 4 + 3];
        osc[o] = cscores[ci];
        olb[o] = 1.0f;
        omk[o] = 1.0f;
    }
    int zstart = nk < TOPK ? nk : TOPK;
    if (tid >= zstart && tid < TOPK) {
        size_t o = (size_t)b * TOPK + tid;
        ob[o * 4 + 0] = 0.0f; ob[o * 4 + 1] = 0.0f;
        ob[o * 4 + 2] = 0.0f; ob[o * 4 + 3] = 0.0f;
        osc[o] = 0.0f;
        olb[o] = 0.0f;
        omk[o] = 0.0f;
    }
}

extern "C" void kernel_launch(void* const* d_in, const int* in_sizes, int n_in,
                              void* d_out, int out_size, void* d_ws, size_t ws_size,
                              hipStream_t stream) {
    const float* boxes_logits = (const float*)d_in[0];
    const float* cls_logits   = (const float*)d_in[1];
    const float* priors       = (const float*)d_in[2];
    int P = in_sizes[2] / 4;
    int B = in_sizes[0] / (P * 4);
    float* out = (float*)d_out;

    // ws layout: [keys B*P u64 | cboxes B*KC*4 f32 | cscores B*KC f32 | cvalid B*KC i32 | coffs B f32]
    // rows (B*KC*16 u64 = 2 MB) reuses the keys region (dead after k_select).
    char* wsb = (char*)d_ws;
    u64*   keys    = (u64*)wsb;
    u64*   rows    = (u64*)wsb;
    size_t off0    = (size_t)B * P * sizeof(u64);
    float* cboxes  = (float*)(wsb + off0);
    float* cscores = (float*)(wsb + off0 + (size_t)B * KC * 4 * sizeof(float));
    int*   cvalid  = (int*)  (wsb + off0 + (size_t)B * KC * 5 * sizeof(float));
    float* coffs   = (float*)(wsb + off0 + (size_t)B * KC * 6 * sizeof(float));

    dim3 g1((P + 255) / 256, B);
    hipLaunchKernelGGL(k_scores, g1, dim3(256), 0, stream, cls_logits, keys, P);
    hipLaunchKernelGGL(k_select, dim3(B), dim3(1024), 0, stream, keys, boxes_logits, priors,
                       cboxes, cscores, cvalid, coffs, P);
    hipLaunchKernelGGL(k_iou, dim3(KC / 16, B), dim3(1024), 0, stream, cboxes, coffs, rows);
    hipLaunchKernelGGL(k_scan, dim3(B), dim3(1024), 0, stream, rows, cboxes, cscores, cvalid,
                       out, B);
}

// Round 3
// 182.577 us; speedup vs baseline: 3.0825x; 1.4527x over previous
//
#include <hip/hip_runtime.h>

typedef unsigned long long u64;
typedef unsigned int u32;

#define KC 1024
#define TOPK 750
#define CONF 0.3f
#define IOU_T 0.01f
#define NBIN 16384          // 14-bit key-prefix histogram
#define WINB 0x2F80u        // LDS window base: scores in (0.3,1] -> bins 0x2FA6..0x2FE0
#define NEGBIN 0x101Fu      // key prefix of masked score -1.0
#define CCAP 2048

// exact f32 op order of the reference softmax + mask; key = (monotone score bits, ~index)
__device__ __forceinline__ u64 score_key(const float* __restrict__ c2, u32 p) {
    float a0 = c2[0], a1 = c2[1];
    float m  = fmaxf(a0, a1);
    float e0 = expf(a0 - m), e1 = expf(a1 - m);
    float s  = e1 / (e0 + e1);
    float ms = s > CONF ? s : -1.0f;
    u32 u = __float_as_uint(ms);
    u32 mapped = (u & 0x80000000u) ? ~u : (u | 0x80000000u);
    return ((u64)mapped << 32) | (u32)(~p);
}

// ---------------- K1: fused score + per-batch 14-bit histogram ----------------
__global__ void k_hist(const float* __restrict__ cls, u32* __restrict__ hist, int P) {
    __shared__ u32 lh[129];
    int t = threadIdx.x;
    if (t < 129) lh[t] = 0;
    __syncthreads();
    int p = blockIdx.x * 256 + t;
    int b = blockIdx.y;
    if (p < P) {
        u64 k = score_key(cls + ((size_t)b * P + p) * 2, (u32)p);
        u32 bin = (u32)(k >> 50);
        if (bin >= WINB && bin < WINB + 128u) atomicAdd(&lh[bin - WINB], 1u);
        else if (bin == NEGBIN)               atomicAdd(&lh[128], 1u);
        else atomicAdd(&hist[(size_t)b * NBIN + bin], 1u);  // provably unreachable; safety
    }
    __syncthreads();
    if (t < 128) { u32 c = lh[t]; if (c) atomicAdd(&hist[(size_t)b * NBIN + WINB + t], c); }
    else if (t == 128) { u32 c = lh[128]; if (c) atomicAdd(&hist[(size_t)b * NBIN + NEGBIN], c); }
}

// ---------------- K2: find cutoff bin (1024th largest key's prefix) ----------------
__global__ __launch_bounds__(1024) void k_cutoff(const u32* __restrict__ hist,
                                                 u32* __restrict__ cut) {
    int b = blockIdx.x, t = threadIdx.x;
    __shared__ u32 suf[2][1024];
    const u32* h = hist + (size_t)b * NBIN;
    u32 hb[16]; u32 local = 0;
    #pragma unroll
    for (int j = 0; j < 16; ++j) { hb[j] = h[t * 16 + j]; local += hb[j]; }
    suf[0][t] = local;
    __syncthreads();
    int src = 0;
    for (int d = 1; d < 1024; d <<= 1) {   // inclusive suffix sums, 10 steps
        suf[src ^ 1][t] = suf[src][t] + ((t + d < 1024) ? suf[src][t + d] : 0u);
        src ^= 1;
        __syncthreads();
    }
    u32 Sinc = suf[src][t];
    u32 Safter = Sinc - local;             // = Sinc(t+1)
    if (Sinc >= KC && Safter < KC) {       // unique crossing thread
        u32 acc = Safter;
        #pragma unroll
        for (int j = 15; j >= 0; --j) {
            acc += hb[j];
            if (acc >= KC) { cut[b] = (u32)(t * 16 + j); break; }
        }
    }
}

// ---------------- K3: compact keys >= cutoff ----------------
__global__ void k_compact(const float* __restrict__ cls, const u32* __restrict__ cut,
                          u32* __restrict__ cnt, u64* __restrict__ cbuf, int P) {
    int p = blockIdx.x * 256 + threadIdx.x;
    int b = blockIdx.y;
    if (p >= P) return;
    u64 k = score_key(cls + ((size_t)b * P + p) * 2, (u32)p);
    if ((u32)(k >> 50) >= cut[b]) {
        u32 pos = atomicAdd(&cnt[b], 1u);
        if (pos < CCAP) cbuf[(size_t)b * CCAP + pos] = k;
    }
}

// ---------------- K4: bitonic sort 2048 + decode + off ----------------
__global__ __launch_bounds__(1024) void k_sortdecode(const u64* __restrict__ cbuf,
        const float* __restrict__ boxes_logits, const float* __restrict__ priors,
        float* __restrict__ cboxes, float* __restrict__ cscores,
        u64* __restrict__ cvw, float* __restrict__ coffs, int P) {
    int b = blockIdx.x, tid = threadIdx.x;
    __shared__ u64 sk[CCAP];
    __shared__ float smax[1024];
    sk[tid]        = cbuf[(size_t)b * CCAP + tid];
    sk[tid + 1024] = cbuf[(size_t)b * CCAP + tid + 1024];
    __syncthreads();
    for (int k = 2; k <= CCAP; k <<= 1) {
        for (int j = k >> 1; j > 0; j >>= 1) {
            int idx = ((tid & ~(j - 1)) << 1) | (tid & (j - 1));
            int par = idx | j;
            u64 a = sk[idx], c = sk[par];
            bool desc = (idx & k) == 0;
            if ((a < c) == desc) { sk[idx] = c; sk[par] = a; }
            __syncthreads();
        }
    }
    u64 key = sk[tid];                    // top-1024, descending (value desc, index asc)
    u32 mapped = (u32)(key >> 32);
    u32 fb = (mapped & 0x80000000u) ? (mapped & 0x7fffffffu) : ~mapped;
    float score = __uint_as_float(fb);
    u32 p = ~(u32)(key & 0xffffffffull);
    bool valid = score > CONF;

    const float* pr4 = priors + (size_t)p * 4;
    const float* lc  = boxes_logits + ((size_t)b * P + p) * 4;
    float pcx = pr4[0], pcy = pr4[1], pw = pr4[2], ph = pr4[3];
    float lx = lc[0], ly = lc[1], lw = lc[2], lh = lc[3];
    float cx = pcx + lx * 0.1f * pw;
    float cy = pcy + ly * 0.1f * ph;
    float w  = pw * expf(lw * 0.2f);
    float h  = ph * expf(lh * 0.2f);
    float t1x = cx - w * 0.5f;
    float t1y = cy - h * 0.5f;
    float x1 = t1x * 1024.0f;
    float y1 = t1y * 1024.0f;
    float x2 = (t1x + w) * 1024.0f;
    float y2 = (t1y + h) * 1024.0f;

    size_t ci = (size_t)b * KC + tid;
    cboxes[ci * 4 + 0] = x1; cboxes[ci * 4 + 1] = y1;
    cboxes[ci * 4 + 2] = x2; cboxes[ci * 4 + 3] = y2;
    cscores[ci] = score;
    u64 bal = __ballot(valid);
    if ((tid & 63) == 0) cvw[(size_t)b * 16 + (tid >> 6)] = bal;

    smax[tid] = valid ? fmaxf(fmaxf(x1, y1), fmaxf(x2, y2)) : 0.0f;
    __syncthreads();
    for (int s = 512; s > 0; s >>= 1) {
        if (tid < s) smax[tid] = fmaxf(smax[tid], smax[tid + s]);
        __syncthreads();
    }
    if (tid == 0) coffs[b] = smax[0] + 1.0f;
}

// ---------------- K5: IoU suppression bitmatrix (full-chip) ----------------
__global__ __launch_bounds__(1024) void k_iou(const float* __restrict__ cboxes,
                                              const float* __restrict__ coffs,
                                              u64* __restrict__ rows) {
    int b = blockIdx.y, tid = threadIdx.x;
    int rowbase = blockIdx.x * 16;
    __shared__ float sx1[KC], sy1[KC], sx2[KC], sy2[KC], sar[KC];
    float off = coffs[b];
    const float* cb = cboxes + (size_t)b * KC * 4;
    float x1 = cb[(size_t)tid * 4 + 0] + off;
    float y1 = cb[(size_t)tid * 4 + 1] + off;
    float x2 = cb[(size_t)tid * 4 + 2] + off;
    float y2 = cb[(size_t)tid * 4 + 3] + off;
    sx1[tid] = x1; sy1[tid] = y1; sx2[tid] = x2; sy2[tid] = y2;
    sar[tid] = (x2 - x1) * (y2 - y1);
    __syncthreads();

    int w = tid >> 6, lane = tid & 63;
    int r = rowbase + w;
    float rx1 = sx1[r], ry1 = sy1[r], rx2 = sx2[r], ry2 = sy2[r], rar = sar[r];
    u64* rb = rows + ((size_t)b * KC + r) * 16;
    #pragma unroll 4
    for (int c = 0; c < 16; ++c) {
        int col = c * 64 + lane;
        float ltx = fmaxf(rx1, sx1[col]), lty = fmaxf(ry1, sy1[col]);
        float rbx = fminf(rx2, sx2[col]), rby = fminf(ry2, sy2[col]);
        float ww = fmaxf(rbx - ltx, 0.0f), hh = fmaxf(rby - lty, 0.0f);
        float inter = ww * hh;
        float uni = rar + sar[col] - inter;
        float iou = inter / fmaxf(uni, 1e-9f);
        bool pred = (iou > IOU_T) && (col != r);
        u64 m = __ballot(pred);
        if (lane == 0) rb[c] = m;
    }
}

// ---------------- K6: skip-list greedy scan + output ----------------
__global__ __launch_bounds__(1024) void k_scan(const u64* __restrict__ rows,
                                               const u64* __restrict__ cvw,
                                               const float* __restrict__ cboxes,
                                               const float* __restrict__ cscores,
                                               float* __restrict__ out, int B) {
    int b = blockIdx.x, tid = threadIdx.x;
    __shared__ u64 keepw[16];
    if (tid < 16) {
        int lane = tid;
        u64 supp = ~cvw[(size_t)b * 16 + lane];   // invalid = pre-suppressed
        u64 kw = 0;
        const u64* rb = rows + (size_t)b * KC * 16;
        for (int w = 0; w < 16; ++w) {
            u64 sw = __shfl(supp, w);
            u64 rem = ~sw;                         // unsuppressed bits in this word
            while (rem) {
                int bit = __ffsll((long long)rem) - 1;   // next kept box
                int i = w * 64 + bit;
                u64 row = rb[(size_t)i * 16 + lane];
                supp |= row;
                if (lane == w) kw |= 1ull << bit;
                sw = __shfl(supp, w);
                u64 above = (bit == 63) ? 0ull : (~0ull << (bit + 1));
                rem = ~sw & above;
            }
        }
        keepw[lane] = kw;
    }
    __syncthreads();

    int wq = tid >> 6, bq = tid & 63;
    u64 myw = keepw[wq];
    bool kept = (myw >> bq) & 1ull;
    int rank = 0, nk = 0;
    #pragma unroll
    for (int w2 = 0; w2 < 16; ++w2) {
        int pc = __popcll(keepw[w2]);
        nk += pc;
        if (w2 < wq) rank += pc;
    }
    rank += __popcll(myw & ((1ull << bq) - 1ull));

    float* ob  = out;
    float* osc = out + (size_t)B * TOPK * 4;
    float* olb = osc + (size_t)B * TOPK;
    float* omk = olb + (size_t)B * TOPK;

    size_t ci = (size_t)b * KC + tid;
    if (kept && rank < TOPK) {
        size_t o = (size_t)b * TOPK + rank;
        ob[o * 4 + 0] = cboxes[ci * 4 + 0];
        ob[o * 4 + 1] = cboxes[ci * 4 + 1];
        ob[o * 4 + 2] = cboxes[ci * 4 + 2];
        ob[o * 4 + 3] = cboxes[ci * 4 + 3];
        osc[o] = cscores[ci];
        olb[o] = 1.0f;
        omk[o] = 1.0f;
    }
    int zstart = nk < TOPK ? nk : TOPK;
    if (tid >= zstart && tid < TOPK) {
        size_t o = (size_t)b * TOPK + tid;
        ob[o * 4 + 0] = 0.0f; ob[o * 4 + 1] = 0.0f;
        ob[o * 4 + 2] = 0.0f; ob[o * 4 + 3] = 0.0f;
        osc[o] = 0.0f;
        olb[o] = 0.0f;
        omk[o] = 0.0f;
    }
}

extern "C" void kernel_launch(void* const* d_in, const int* in_sizes, int n_in,
                              void* d_out, int out_size, void* d_ws, size_t ws_size,
                              hipStream_t stream) {
    const float* boxes_logits = (const float*)d_in[0];
    const float* cls_logits   = (const float*)d_in[1];
    const float* priors       = (const float*)d_in[2];
    int P = in_sizes[2] / 4;
    int B = in_sizes[0] / (P * 4);
    float* out = (float*)d_out;
    char* wsb = (char*)d_ws;

    // region A [0, 2MB): hist(1MB)+cnt+cut, later overlaid by rows(2MB)
    size_t HIST_B = (size_t)B * NBIN * sizeof(u32);           // 1,048,576
    size_t ROWS_B = (size_t)B * KC * 16 * sizeof(u64);        // 2,097,152
    size_t CBUF_B = (size_t)B * CCAP * sizeof(u64);           //   262,144
    u32* hist = (u32*)wsb;
    u32* cnt  = (u32*)(wsb + HIST_B);
    u32* cut  = (u32*)(wsb + HIST_B + 128);
    u64* rows = (u64*)wsb;
    u64* cbuf = (u64*)(wsb + ROWS_B);
    float* cboxes  = (float*)(wsb + ROWS_B + CBUF_B);
    float* cscores = cboxes + (size_t)B * KC * 4;
    u64*   cvw     = (u64*)(cscores + (size_t)B * KC);
    float* coffs   = (float*)(cvw + (size_t)B * 16);
    // total ~2.6 MB of ws

    hipMemsetAsync(wsb, 0, HIST_B + 256, stream);             // hist + cnt (+cut slack)
    hipMemsetAsync(wsb + ROWS_B, 0, CBUF_B, stream);          // cbuf zero padding

    dim3 gP((P + 255) / 256, B);
    hipLaunchKernelGGL(k_hist,       gP,              dim3(256),  0, stream, cls_logits, hist, P);
    hipLaunchKernelGGL(k_cutoff,     dim3(B),         dim3(1024), 0, stream, hist, cut);
    hipLaunchKernelGGL(k_compact,    gP,              dim3(256),  0, stream, cls_logits, cut, cnt, cbuf, P);
    hipLaunchKernelGGL(k_sortdecode, dim3(B),         dim3(1024), 0, stream, cbuf, boxes_logits, priors,
                       cboxes, cscores, cvw, coffs, P);
    hipLaunchKernelGGL(k_iou,        dim3(KC / 16, B), dim3(1024), 0, stream, cboxes, coffs, rows);
    hipLaunchKernelGGL(k_scan,       dim3(B),         dim3(1024), 0, stream, rows, cvw, cboxes, cscores, out, B);
}

// Round 4
// 125.589 us; speedup vs baseline: 4.4812x; 1.4538x over previous
//
#include <hip/hip_runtime.h>

typedef unsigned long long u64;
typedef unsigned int u32;

#define KC 1024
#define TOPK 750
#define CONF 0.3f
#define IOU_T 0.01f
#define NBIN 16384          // 14-bit key-prefix histogram
#define WINB 0x2F80u        // LDS window base: scores in (0.3,1] -> bins 0x2FA6..0x2FE0
#define NEGBIN 0x101Fu      // key prefix of masked score -1.0
#define CCAP 2048
#define CNT_STRIDE 64       // u32 stride between per-batch counters (256B, no false sharing)

// exact f32 op order of the reference softmax + mask; key = (monotone score bits, ~index)
__device__ __forceinline__ u64 score_key(const float* __restrict__ c2, u32 p) {
    float a0 = c2[0], a1 = c2[1];
    float m  = fmaxf(a0, a1);
    float e0 = expf(a0 - m), e1 = expf(a1 - m);
    float s  = e1 / (e0 + e1);
    float ms = s > CONF ? s : -1.0f;
    u32 u = __float_as_uint(ms);
    u32 mapped = (u & 0x80000000u) ? ~u : (u | 0x80000000u);
    return ((u64)mapped << 32) | (u32)(~p);
}

// ---------------- K1: fused score + per-batch 14-bit histogram ----------------
__global__ __launch_bounds__(1024) void k_hist(const float* __restrict__ cls,
                                               u32* __restrict__ hist, int P) {
    __shared__ u32 lh[129];
    int t = threadIdx.x;
    if (t < 129) lh[t] = 0;
    __syncthreads();
    int p = blockIdx.x * 1024 + t;
    int b = blockIdx.y;
    if (p < P) {
        u64 k = score_key(cls + ((size_t)b * P + p) * 2, (u32)p);
        u32 bin = (u32)(k >> 50);
        if (bin >= WINB && bin < WINB + 128u) atomicAdd(&lh[bin - WINB], 1u);
        else if (bin == NEGBIN)               atomicAdd(&lh[128], 1u);
        else atomicAdd(&hist[(size_t)b * NBIN + bin], 1u);  // provably unreachable; safety
    }
    __syncthreads();
    if (t < 128) { u32 c = lh[t]; if (c) atomicAdd(&hist[(size_t)b * NBIN + WINB + t], c); }
    else if (t == 128) { u32 c = lh[128]; if (c) atomicAdd(&hist[(size_t)b * NBIN + NEGBIN], c); }
}

// ---------------- K2: find cutoff bin (1024th largest key's prefix) ----------------
__global__ __launch_bounds__(1024) void k_cutoff(const u32* __restrict__ hist,
                                                 u32* __restrict__ cut) {
    int b = blockIdx.x, t = threadIdx.x;
    __shared__ u32 suf[2][1024];
    const u32* h = hist + (size_t)b * NBIN;
    u32 hb[16]; u32 local = 0;
    #pragma unroll
    for (int j = 0; j < 16; ++j) { hb[j] = h[t * 16 + j]; local += hb[j]; }
    suf[0][t] = local;
    __syncthreads();
    int src = 0;
    for (int d = 1; d < 1024; d <<= 1) {   // inclusive suffix sums, 10 steps
        suf[src ^ 1][t] = suf[src][t] + ((t + d < 1024) ? suf[src][t + d] : 0u);
        src ^= 1;
        __syncthreads();
    }
    u32 Sinc = suf[src][t];
    u32 Safter = Sinc - local;             // = Sinc(t+1)
    if (Sinc >= KC && Safter < KC) {       // unique crossing thread
        u32 acc = Safter;
        #pragma unroll
        for (int j = 15; j >= 0; --j) {
            acc += hb[j];
            if (acc >= KC) { cut[b] = (u32)(t * 16 + j); break; }
        }
    }
}

// ---------------- K3: compact keys >= cutoff (wave-aggregated atomics) ----------------
__global__ void k_compact(const float* __restrict__ cls, const u32* __restrict__ cut,
                          u32* __restrict__ cnt, u64* __restrict__ cbuf, int P) {
    int p = blockIdx.x * 256 + threadIdx.x;
    int b = blockIdx.y;
    int lane = threadIdx.x & 63;
    bool match = false;
    u64 k = 0;
    if (p < P) {
        k = score_key(cls + ((size_t)b * P + p) * 2, (u32)p);
        match = ((u32)(k >> 50) >= cut[b]);
    }
    u64 bal = __ballot(match);
    u32 base = 0;
    if (lane == 0 && bal) base = atomicAdd(&cnt[(size_t)b * CNT_STRIDE], (u32)__popcll(bal));
    base = (u32)__shfl((int)base, 0);
    if (match) {
        u32 idx = base + (u32)__popcll(bal & ((1ull << lane) - 1ull));
        if (idx < CCAP) cbuf[(size_t)b * CCAP + idx] = k;
    }
}

// ---------------- K4: bitonic sort 2048 + decode + off ----------------
__global__ __launch_bounds__(1024) void k_sortdecode(const u64* __restrict__ cbuf,
        const float* __restrict__ boxes_logits, const float* __restrict__ priors,
        float* __restrict__ cboxes, float* __restrict__ cscores,
        u64* __restrict__ cvw, float* __restrict__ coffs, int P) {
    int b = blockIdx.x, tid = threadIdx.x;
    __shared__ u64 sk[CCAP];
    __shared__ float smax[1024];
    sk[tid]        = cbuf[(size_t)b * CCAP + tid];
    sk[tid + 1024] = cbuf[(size_t)b * CCAP + tid + 1024];
    __syncthreads();
    for (int k = 2; k <= CCAP; k <<= 1) {
        for (int j = k >> 1; j > 0; j >>= 1) {
            int idx = ((tid & ~(j - 1)) << 1) | (tid & (j - 1));
            int par = idx | j;
            u64 a = sk[idx], c = sk[par];
            bool desc = (idx & k) == 0;
            if ((a < c) == desc) { sk[idx] = c; sk[par] = a; }
            __syncthreads();
        }
    }
    u64 key = sk[tid];                    // top-1024, descending (value desc, index asc)
    u32 mapped = (u32)(key >> 32);
    u32 fb = (mapped & 0x80000000u) ? (mapped & 0x7fffffffu) : ~mapped;
    float score = __uint_as_float(fb);
    u32 p = ~(u32)(key & 0xffffffffull);
    bool valid = score > CONF;

    const float* pr4 = priors + (size_t)p * 4;
    const float* lc  = boxes_logits + ((size_t)b * P + p) * 4;
    float pcx = pr4[0], pcy = pr4[1], pw = pr4[2], ph = pr4[3];
    float lx = lc[0], ly = lc[1], lw = lc[2], lh = lc[3];
    float cx = pcx + lx * 0.1f * pw;
    float cy = pcy + ly * 0.1f * ph;
    float w  = pw * expf(lw * 0.2f);
    float h  = ph * expf(lh * 0.2f);
    float t1x = cx - w * 0.5f;
    float t1y = cy - h * 0.5f;
    float x1 = t1x * 1024.0f;
    float y1 = t1y * 1024.0f;
    float x2 = (t1x + w) * 1024.0f;
    float y2 = (t1y + h) * 1024.0f;

    size_t ci = (size_t)b * KC + tid;
    cboxes[ci * 4 + 0] = x1; cboxes[ci * 4 + 1] = y1;
    cboxes[ci * 4 + 2] = x2; cboxes[ci * 4 + 3] = y2;
    cscores[ci] = score;
    u64 bal = __ballot(valid);
    if ((tid & 63) == 0) cvw[(size_t)b * 16 + (tid >> 6)] = bal;

    smax[tid] = valid ? fmaxf(fmaxf(x1, y1), fmaxf(x2, y2)) : 0.0f;
    __syncthreads();
    for (int s = 512; s > 0; s >>= 1) {
        if (tid < s) smax[tid] = fmaxf(smax[tid], smax[tid + s]);
        __syncthreads();
    }
    if (tid == 0) coffs[b] = smax[0] + 1.0f;
}

// ---------------- K5: IoU suppression bitmatrix (full-chip) ----------------
__global__ __launch_bounds__(1024) void k_iou(const float* __restrict__ cboxes,
                                              const float* __restrict__ coffs,
                                              u64* __restrict__ rows) {
    int b = blockIdx.y, tid = threadIdx.x;
    int rowbase = blockIdx.x * 16;
    __shared__ float sx1[KC], sy1[KC], sx2[KC], sy2[KC], sar[KC];
    float off = coffs[b];
    const float* cb = cboxes + (size_t)b * KC * 4;
    float x1 = cb[(size_t)tid * 4 + 0] + off;
    float y1 = cb[(size_t)tid * 4 + 1] + off;
    float x2 = cb[(size_t)tid * 4 + 2] + off;
    float y2 = cb[(size_t)tid * 4 + 3] + off;
    sx1[tid] = x1; sy1[tid] = y1; sx2[tid] = x2; sy2[tid] = y2;
    sar[tid] = (x2 - x1) * (y2 - y1);
    __syncthreads();

    int w = tid >> 6, lane = tid & 63;
    int r = rowbase + w;
    float rx1 = sx1[r], ry1 = sy1[r], rx2 = sx2[r], ry2 = sy2[r], rar = sar[r];
    u64* rb = rows + ((size_t)b * KC + r) * 16;
    #pragma unroll 4
    for (int c = 0; c < 16; ++c) {
        int col = c * 64 + lane;
        float ltx = fmaxf(rx1, sx1[col]), lty = fmaxf(ry1, sy1[col]);
        float rbx = fminf(rx2, sx2[col]), rby = fminf(ry2, sy2[col]);
        float ww = fmaxf(rbx - ltx, 0.0f), hh = fmaxf(rby - lty, 0.0f);
        float inter = ww * hh;
        float uni = rar + sar[col] - inter;
        float iou = inter / fmaxf(uni, 1e-9f);
        bool pred = (iou > IOU_T) && (col != r);
        u64 m = __ballot(pred);
        if (lane == 0) rb[c] = m;
    }
}

// ---------------- K6: skip-list greedy scan + output ----------------
__global__ __launch_bounds__(1024) void k_scan(const u64* __restrict__ rows,
                                               const u64* __restrict__ cvw,
                                               const float* __restrict__ cboxes,
                                               const float* __restrict__ cscores,
                                               float* __restrict__ out, int B) {
    int b = blockIdx.x, tid = threadIdx.x;
    __shared__ u64 keepw[16];
    if (tid < 16) {
        int lane = tid;
        u64 supp = ~cvw[(size_t)b * 16 + lane];   // invalid = pre-suppressed
        u64 kw = 0;
        const u64* rb = rows + (size_t)b * KC * 16;
        for (int w = 0; w < 16; ++w) {
            u64 sw = __shfl(supp, w);
            u64 rem = ~sw;                         // unsuppressed bits in this word
            while (rem) {
                int bit = __ffsll((long long)rem) - 1;   // next kept box
                int i = w * 64 + bit;
                u64 row = rb[(size_t)i * 16 + lane];
                supp |= row;
                if (lane == w) kw |= 1ull << bit;
                sw = __shfl(supp, w);
                u64 above = (bit == 63) ? 0ull : (~0ull << (bit + 1));
                rem = ~sw & above;
            }
        }
        keepw[lane] = kw;
    }
    __syncthreads();

    int wq = tid >> 6, bq = tid & 63;
    u64 myw = keepw[wq];
    bool kept = (myw >> bq) & 1ull;
    int rank = 0, nk = 0;
    #pragma unroll
    for (int w2 = 0; w2 < 16; ++w2) {
        int pc = __popcll(keepw[w2]);
        nk += pc;
        if (w2 < wq) rank += pc;
    }
    rank += __popcll(myw & ((1ull << bq) - 1ull));

    float* ob  = out;
    float* osc = out + (size_t)B * TOPK * 4;
    float* olb = osc + (size_t)B * TOPK;
    float* omk = olb + (size_t)B * TOPK;

    size_t ci = (size_t)b * KC + tid;
    if (kept && rank < TOPK) {
        size_t o = (size_t)b * TOPK + rank;
        ob[o * 4 + 0] = cboxes[ci * 4 + 0];
        ob[o * 4 + 1] = cboxes[ci * 4 + 1];
        ob[o * 4 + 2] = cboxes[ci * 4 + 2];
        ob[o * 4 + 3] = cboxes[ci * 4 + 3];
        osc[o] = cscores[ci];
        olb[o] = 1.0f;
        omk[o] = 1.0f;
    }
    int zstart = nk < TOPK ? nk : TOPK;
    if (tid >= zstart && tid < TOPK) {
        size_t o = (size_t)b * TOPK + tid;
        ob[o * 4 + 0] = 0.0f; ob[o * 4 + 1] = 0.0f;
        ob[o * 4 + 2] = 0.0f; ob[o * 4 + 3] = 0.0f;
        osc[o] = 0.0f;
        olb[o] = 0.0f;
        omk[o] = 0.0f;
    }
}

extern "C" void kernel_launch(void* const* d_in, const int* in_sizes, int n_in,
                              void* d_out, int out_size, void* d_ws, size_t ws_size,
                              hipStream_t stream) {
    const float* boxes_logits = (const float*)d_in[0];
    const float* cls_logits   = (const float*)d_in[1];
    const float* priors       = (const float*)d_in[2];
    int P = in_sizes[2] / 4;
    int B = in_sizes[0] / (P * 4);
    float* out = (float*)d_out;
    char* wsb = (char*)d_ws;

    // region A [0, 2MB): hist(1MB)+cnt(4KB)+cut(64B), later overlaid by rows(2MB)
    size_t HIST_B = (size_t)B * NBIN * sizeof(u32);           // 1,048,576
    size_t CNT_B  = (size_t)B * CNT_STRIDE * sizeof(u32);     //     4,096
    size_t ROWS_B = (size_t)B * KC * 16 * sizeof(u64);        // 2,097,152
    size_t CBUF_B = (size_t)B * CCAP * sizeof(u64);           //   262,144
    u32* hist = (u32*)wsb;
    u32* cnt  = (u32*)(wsb + HIST_B);
    u32* cut  = (u32*)(wsb + HIST_B + CNT_B);
    u64* rows = (u64*)wsb;
    u64* cbuf = (u64*)(wsb + ROWS_B);
    float* cboxes  = (float*)(wsb + ROWS_B + CBUF_B);
    float* cscores = cboxes + (size_t)B * KC * 4;
    u64*   cvw     = (u64*)(cscores + (size_t)B * KC);
    float* coffs   = (float*)(cvw + (size_t)B * 16);
    // total ~2.6 MB of ws

    hipMemsetAsync(wsb, 0, HIST_B + CNT_B + 256, stream);     // hist + cnt + cut slack
    hipMemsetAsync(wsb + ROWS_B, 0, CBUF_B, stream);          // cbuf zero padding

    dim3 gH((P + 1023) / 1024, B);
    dim3 gC((P + 255) / 256, B);
    hipLaunchKernelGGL(k_hist,       gH,               dim3(1024), 0, stream, cls_logits, hist, P);
    hipLaunchKernelGGL(k_cutoff,     dim3(B),          dim3(1024), 0, stream, hist, cut);
    hipLaunchKernelGGL(k_compact,    gC,               dim3(256),  0, stream, cls_logits, cut, cnt, cbuf, P);
    hipLaunchKernelGGL(k_sortdecode, dim3(B),          dim3(1024), 0, stream, cbuf, boxes_logits, priors,
                       cboxes, cscores, cvw, coffs, P);
    hipLaunchKernelGGL(k_iou,        dim3(KC / 16, B), dim3(1024), 0, stream, cboxes, coffs, rows);
    hipLaunchKernelGGL(k_scan,       dim3(B),          dim3(1024), 0, stream, rows, cvw, cboxes, cscores, out, B);
}